// Round 7
// baseline (1741.289 us; speedup 1.0000x reference)
//
#include <hip/hip_runtime.h>
#include <math.h>

// Problem constants (N=2, C=64, H=96, W=96, PATCH=3)
static constexpr int NITEM = 2;
static constexpr int C = 64;
static constexpr int H = 96;
static constexpr int W = 96;
static constexpr int HW = H * W;         // 9216 pixels
static constexpr int HP = 94;            // H - 3 + 1
static constexpr int NP = HP * HP;       // 8836 patch positions

// ---- factored-path constants ----
static constexpr int BRY = 8;                       // ref patch-rows per band
static constexpr int NBAND = (HP + BRY - 1) / BRY;  // 12
static constexpr int PYB = BRY + 2;                 // pixel rows per band = 10
static constexpr int S1ROWS = PYB * W;              // 960 S1 rows per item per band
static constexpr int TS = 126;                      // S1 output tile (compute 128 with +2 halo)
static constexpr int NPT = (HW - 2 + TS - 1) / TS;  // 74 p-tiles
static constexpr int NQT = (S1ROWS - 2 + TS - 1) / TS; // 8 q-tiles
static constexpr int ITILE = 256;                   // i's per pass2 block (1 per thread)
static constexpr int NIT = (NP + ITILE - 1) / ITILE; // 35
static constexpr int PAD = 132;                     // LDS row pad
static constexpr int KSPLIT = 32;                   // K staged per round (LDS halving)

// ---- fallback (R4 direct) constants ----
static constexpr int NSEG = 8;
static constexpr int SEGLEN = (NP + NSEG - 1) / NSEG; // 1105
static constexpr int MT = 128;
static constexpr int NT = 128;
static constexpr int KC = 16;
static constexpr int LDP = MT + 4;
static constexpr int NMTILE = (NP + MT - 1) / MT;   // 70

// ---------------- Kernel 1: per-pixel channel L2 normalize + NCHW->NHWC ----------------
__global__ __launch_bounds__(256) void normalize_kernel(
    const float* __restrict__ f1, const float* __restrict__ f2,
    float* __restrict__ fiN, float* __restrict__ frN, float* __restrict__ ssn)
{
    int t = blockIdx.x * 256 + threadIdx.x;
    const int perTensor = NITEM * HW;
    if (t >= 2 * perTensor) return;
    int which = t / perTensor;
    int p = t - which * perTensor;
    int n = p / HW;
    int pix = p - n * HW;
    const float* src = (which ? f2 : f1) + (size_t)n * C * HW + pix;
    float s = 0.f;
    #pragma unroll
    for (int c = 0; c < C; c++) {
        float v = src[c * HW];
        s = fmaf(v, v, s);
    }
    float norm = sqrtf(s);
    float scale = 1.0f / fmaxf(norm, 1e-12f);
    float* dst = (which ? frN : fiN) + (size_t)p * C;
    #pragma unroll
    for (int c = 0; c < C; c++) {
        dst[c] = src[c * HW] * scale;
    }
    if (which) ssn[p] = s * scale * scale;
}

// ---------------- Kernel 2: ref patch inverse norms ----------------
__global__ __launch_bounds__(256) void refnorm_kernel(
    const float* __restrict__ ssn, float* __restrict__ invn)
{
    int t = blockIdx.x * 256 + threadIdx.x;
    if (t >= NITEM * NP) return;
    int n = t / NP;
    int r = t - n * NP;
    int yr = r / HP, xr = r - yr * HP;
    const float* s = ssn + n * HW;
    float acc = 0.f;
    #pragma unroll
    for (int dy = 0; dy < 3; dy++)
        #pragma unroll
        for (int dx = 0; dx < 3; dx++)
            acc += s[(yr + dy) * W + (xr + dx)];
    invn[t] = 1.0f / (sqrtf(acc) + 1e-5f);
}

// ================= FACTORED PATH =================
// Kernel A: band GEMM (pixel correlations, K=64) + fused dx-diagonal 3-sum epilogue.
// S1[n][qL][p] = sum_dx P[ry0*96+qL+dx][p+dx], P[q][p] = sum_c frN[q][c]*fiN[p][c].
// LDS halved vs R6: K staged in 2 rounds of 32; epilogue P-tile in 2 row-halves.
// Union = 34.8 KB -> 4 blocks/CU (was 67.5 KB -> 2 blocks/CU).
__global__ __launch_bounds__(256) void gemmS1_kernel(
    const float* __restrict__ fiN, const float* __restrict__ frN,
    float* __restrict__ s1, int ry0)
{
    __shared__ union SM {
        struct { float Aq[KSPLIT][PAD]; float Bp[KSPLIT][PAD]; } g;  // 2 x 16896 B
        struct { float pt[66][PAD]; } e;                             // 34848 B
    } sm;

    const int t = threadIdx.x;
    const int pt0 = blockIdx.x * TS;     // global pixel col base
    const int qt0 = blockIdx.y * TS;     // band-local q base
    const int n = blockIdx.z;

    const float* fa = frN + (size_t)n * HW * C;  // q side (ref)
    const float* fb = fiN + (size_t)n * HW * C;  // p side (input)

    // staging pixel indices (rows lrow, lrow+64), 8 channels per thread per round
    const int lrow = t >> 2;
    const int c8 = (t & 3) * 8;
    int qpix0 = ry0 * W + qt0 + lrow;      if (qpix0 > HW - 1) qpix0 = HW - 1;
    int qpix1 = ry0 * W + qt0 + lrow + 64; if (qpix1 > HW - 1) qpix1 = HW - 1;
    int ppix0 = pt0 + lrow;                if (ppix0 > HW - 1) ppix0 = HW - 1;
    int ppix1 = pt0 + lrow + 64;           if (ppix1 > HW - 1) ppix1 = HW - 1;

    const int tm4 = (t & 15) * 4;
    const int tn4 = (t >> 4) * 4;
    float acc[8][8];
    #pragma unroll
    for (int i = 0; i < 8; i++)
        #pragma unroll
        for (int j = 0; j < 8; j++) acc[i][j] = 0.f;

    // ---- GEMM in 2 K-rounds of 32 (accumulation order identical to monolithic K=64)
    #pragma unroll 1
    for (int kb = 0; kb < C; kb += KSPLIT) {
        if (kb) __syncthreads();   // previous round's LDS reads complete
        {
            const float* qa0 = fa + (size_t)qpix0 * C + kb + c8;
            const float* qa1 = fa + (size_t)qpix1 * C + kb + c8;
            const float* pb0 = fb + (size_t)ppix0 * C + kb + c8;
            const float* pb1 = fb + (size_t)ppix1 * C + kb + c8;
            #pragma unroll
            for (int u = 0; u < 2; u++) {
                float4 va0 = *(const float4*)(qa0 + 4 * u);
                float4 va1 = *(const float4*)(qa1 + 4 * u);
                float4 vb0 = *(const float4*)(pb0 + 4 * u);
                float4 vb1 = *(const float4*)(pb1 + 4 * u);
                int kk = c8 + 4 * u;
                sm.g.Aq[kk + 0][lrow] = va0.x; sm.g.Aq[kk + 1][lrow] = va0.y;
                sm.g.Aq[kk + 2][lrow] = va0.z; sm.g.Aq[kk + 3][lrow] = va0.w;
                sm.g.Aq[kk + 0][lrow + 64] = va1.x; sm.g.Aq[kk + 1][lrow + 64] = va1.y;
                sm.g.Aq[kk + 2][lrow + 64] = va1.z; sm.g.Aq[kk + 3][lrow + 64] = va1.w;
                sm.g.Bp[kk + 0][lrow] = vb0.x; sm.g.Bp[kk + 1][lrow] = vb0.y;
                sm.g.Bp[kk + 2][lrow] = vb0.z; sm.g.Bp[kk + 3][lrow] = vb0.w;
                sm.g.Bp[kk + 0][lrow + 64] = vb1.x; sm.g.Bp[kk + 1][lrow + 64] = vb1.y;
                sm.g.Bp[kk + 2][lrow + 64] = vb1.z; sm.g.Bp[kk + 3][lrow + 64] = vb1.w;
            }
        }
        __syncthreads();

        #pragma unroll
        for (int k = 0; k < KSPLIT; k++) {
            float4 af0 = *(const float4*)&sm.g.Aq[k][tm4];
            float4 af1 = *(const float4*)&sm.g.Aq[k][tm4 + 64];
            float4 bf0 = *(const float4*)&sm.g.Bp[k][tn4];
            float4 bf1 = *(const float4*)&sm.g.Bp[k][tn4 + 64];
            float av[8] = {af0.x, af0.y, af0.z, af0.w, af1.x, af1.y, af1.z, af1.w};
            float bw[8] = {bf0.x, bf0.y, bf0.z, bf0.w, bf1.x, bf1.y, bf1.z, bf1.w};
            #pragma unroll
            for (int i = 0; i < 8; i++)
                #pragma unroll
                for (int j = 0; j < 8; j++)
                    acc[i][j] = fmaf(av[i], bw[j], acc[i][j]);
        }
    }

    float* s1n = s1 + (size_t)n * S1ROWS * HW;
    const int pp = t & 127;
    const int qhalf = t >> 7;

    // ---- epilogue half 0: P rows 0..65 in LDS, write S1 qq in 0..63
    __syncthreads();
    #pragma unroll
    for (int i = 0; i < 4; i++) {
        int row = tm4 + i;
        *(float4*)&sm.e.pt[row][tn4] = make_float4(acc[i][0], acc[i][1], acc[i][2], acc[i][3]);
        *(float4*)&sm.e.pt[row][tn4 + 64] = make_float4(acc[i][4], acc[i][5], acc[i][6], acc[i][7]);
    }
    if (tm4 == 0) {
        #pragma unroll
        for (int i = 4; i < 6; i++) {   // halo rows 64, 65
            int row = 60 + i;
            *(float4*)&sm.e.pt[row][tn4] = make_float4(acc[i][0], acc[i][1], acc[i][2], acc[i][3]);
            *(float4*)&sm.e.pt[row][tn4 + 64] = make_float4(acc[i][4], acc[i][5], acc[i][6], acc[i][7]);
        }
    }
    __syncthreads();
    if (pp < TS) {
        for (int qq = qhalf; qq < 64; qq += 2) {
            int qL = qt0 + qq;
            int pG = pt0 + pp;
            if (qL < S1ROWS && pG < HW) {
                float v = sm.e.pt[qq][pp] + sm.e.pt[qq + 1][pp + 1] + sm.e.pt[qq + 2][pp + 2];
                s1n[(size_t)qL * HW + pG] = v;
            }
        }
    }

    // ---- epilogue half 1: P rows 64..127 (local 0..63), write S1 qq in 64..125
    __syncthreads();
    #pragma unroll
    for (int i = 4; i < 8; i++) {
        int row = tm4 + (i - 4);        // global row tm4+64+(i-4), local -64
        *(float4*)&sm.e.pt[row][tn4] = make_float4(acc[i][0], acc[i][1], acc[i][2], acc[i][3]);
        *(float4*)&sm.e.pt[row][tn4 + 64] = make_float4(acc[i][4], acc[i][5], acc[i][6], acc[i][7]);
    }
    __syncthreads();
    if (pp < TS) {
        for (int qq = 64 + qhalf; qq < TS; qq += 2) {
            int qL = qt0 + qq;
            int pG = pt0 + pp;
            if (qL < S1ROWS && pG < HW) {
                int lq = qq - 64;
                float v = sm.e.pt[lq][pp] + sm.e.pt[lq + 1][pp + 1] + sm.e.pt[lq + 2][pp + 2];
                s1n[(size_t)qL * HW + pG] = v;
            }
        }
    }
}

// Kernel B: dy-diagonal 3-sum + patch-norm scale + per-ry running argmax.
// grid (BRYb, 35 i-tiles, 2 items), one i per thread.
__global__ __launch_bounds__(256) void pass2_kernel(
    const float* __restrict__ s1, const float* __restrict__ invn,
    float* __restrict__ pbv, int* __restrict__ pbi, int ry0)
{
    const int t = threadIdx.x;
    const int ryL = blockIdx.x;          // band-local ref patch-row
    const int ry = ry0 + ryL;            // global ref patch-row
    const int n = blockIdx.z;
    const int i = blockIdx.y * ITILE + t;
    if (i >= NP) return;

    const float* s1n = s1 + (size_t)n * S1ROWS * HW;
    const float* inv = invn + (size_t)n * NP + ry * HP;
    const int rBase = ry * HP;

    int iy = i / HP, ix = i - iy * HP;
    int ppix = iy * W + ix;
    const float* r0 = s1n + (size_t)(ryL * W) * HW + ppix;               // dy=0
    const float* r1 = r0 + (size_t)W * HW + W;                           // dy=1
    const float* r2 = r1 + (size_t)W * HW + W;                           // dy=2

    float bv = -INFINITY;
    int brx = 0;
    #pragma unroll 4
    for (int rx = 0; rx < HP; rx++) {
        float v = (r0[(size_t)rx * HW] + r1[(size_t)rx * HW] + r2[(size_t)rx * HW]) * inv[rx];
        if (v > bv) { bv = v; brx = rx; }
    }
    size_t o = ((size_t)n * HP + ry) * NP + i;
    pbv[o] = bv;
    pbi[o] = rBase + brx;
}

// Reduce over 94 ry partials -> flow (lexicographic: first global max)
__global__ __launch_bounds__(256) void reduce94_kernel(
    const float* __restrict__ pbv, const int* __restrict__ pbi,
    float* __restrict__ flowh, float* __restrict__ floww)
{
    int t = blockIdx.x * 256 + threadIdx.x;
    if (t >= NITEM * NP) return;
    int n = t / NP;
    int i = t - n * NP;
    const float* bvp = pbv + (size_t)n * HP * NP;
    const int* bip = pbi + (size_t)n * HP * NP;
    float v = bvp[i];
    int idx = bip[i];
    for (int s = 1; s < HP; s++) {
        float v2 = bvp[(size_t)s * NP + i];
        int i2 = bip[(size_t)s * NP + i];
        if (v2 > v || (v2 == v && i2 < idx)) { v = v2; idx = i2; }
    }
    int yi = i / HP, xi = i - yi * HP;
    int yr = idx / HP, xr = idx - yr * HP;
    flowh[t] = (float)(yr - yi);
    floww[t] = (float)(xr - xi);
}

// ================= FALLBACK PATH (R4 direct, proven) =================
__global__ __launch_bounds__(256) void corr_kernel(
    const float* __restrict__ fiN, const float* __restrict__ frN,
    const float* __restrict__ invn,
    float* __restrict__ bestv, int* __restrict__ besti)
{
    __shared__ union SM {
        struct { float A[KC][LDP]; float B[KC][LDP]; } g;
        struct { float rv[MT][16]; int ri[MT][16]; } red;
    } sm;

    const int t = threadIdx.x;
    const int itile = blockIdx.x;
    const int seg = blockIdx.y;
    const int n = blockIdx.z;

    const float* fa = fiN + (size_t)n * HW * C;
    const float* fb = frN + (size_t)n * HW * C;
    const float* inv = invn + (size_t)n * NP;

    const int lrow = t >> 2;
    const int lc = (t & 3) * 4;

    int ia0 = itile * MT + lrow;      if (ia0 > NP - 1) ia0 = NP - 1;
    int ia1 = itile * MT + lrow + 64; if (ia1 > NP - 1) ia1 = NP - 1;
    const int ay0 = ia0 / HP, ax0 = ia0 - ay0 * HP;
    const int ay1 = ia1 / HP, ax1 = ia1 - ay1 * HP;
    const int aoff0 = (ay0 * W + ax0) * C;
    const int aoff1 = (ay1 * W + ax1) * C;

    const int tm4 = (t & 15) * 4;
    const int tn4 = (t >> 4) * 4;

    const int segStart = seg * SEGLEN;
    const int segEnd = (segStart + SEGLEN < NP) ? segStart + SEGLEN : NP;

    float bv[8];
    int bi[8];
    #pragma unroll
    for (int i = 0; i < 8; i++) { bv[i] = -INFINITY; bi[i] = 0; }

    for (int rt = segStart; rt < segEnd; rt += NT) {
        int ib0 = rt + lrow;      if (ib0 > NP - 1) ib0 = NP - 1;
        int ib1 = rt + lrow + 64; if (ib1 > NP - 1) ib1 = NP - 1;
        const int by0 = ib0 / HP, bx0 = ib0 - by0 * HP;
        const int by1 = ib1 / HP, bx1 = ib1 - by1 * HP;
        const int boff0 = (by0 * W + bx0) * C;
        const int boff1 = (by1 * W + bx1) * C;

        float acc[8][8];
        #pragma unroll
        for (int i = 0; i < 8; i++)
            #pragma unroll
            for (int j = 0; j < 8; j++) acc[i][j] = 0.f;

        float4 a0 = *(const float4*)(fa + aoff0 + lc);
        float4 a1 = *(const float4*)(fa + aoff1 + lc);
        float4 b0 = *(const float4*)(fb + boff0 + lc);
        float4 b1 = *(const float4*)(fb + boff1 + lc);

        #pragma unroll 1
        for (int ch = 0; ch < 36; ch++) {
            __syncthreads();
            sm.g.A[lc + 0][lrow] = a0.x; sm.g.A[lc + 1][lrow] = a0.y;
            sm.g.A[lc + 2][lrow] = a0.z; sm.g.A[lc + 3][lrow] = a0.w;
            sm.g.A[lc + 0][lrow + 64] = a1.x; sm.g.A[lc + 1][lrow + 64] = a1.y;
            sm.g.A[lc + 2][lrow + 64] = a1.z; sm.g.A[lc + 3][lrow + 64] = a1.w;
            sm.g.B[lc + 0][lrow] = b0.x; sm.g.B[lc + 1][lrow] = b0.y;
            sm.g.B[lc + 2][lrow] = b0.z; sm.g.B[lc + 3][lrow] = b0.w;
            sm.g.B[lc + 0][lrow + 64] = b1.x; sm.g.B[lc + 1][lrow + 64] = b1.y;
            sm.g.B[lc + 2][lrow + 64] = b1.z; sm.g.B[lc + 3][lrow + 64] = b1.w;
            __syncthreads();

            if (ch < 35) {
                const int chn = ch + 1;
                const int pp = chn >> 2;
                const int c0 = (chn & 3) << 4;
                const int dy = pp / 3, dx = pp - dy * 3;
                const int poff = (dy * W + dx) * C + c0 + lc;
                a0 = *(const float4*)(fa + aoff0 + poff);
                a1 = *(const float4*)(fa + aoff1 + poff);
                b0 = *(const float4*)(fb + boff0 + poff);
                b1 = *(const float4*)(fb + boff1 + poff);
            }

            #pragma unroll
            for (int k = 0; k < KC; k++) {
                float4 af0 = *(const float4*)&sm.g.A[k][tm4];
                float4 af1 = *(const float4*)&sm.g.A[k][tm4 + 64];
                float4 bf0 = *(const float4*)&sm.g.B[k][tn4];
                float4 bf1 = *(const float4*)&sm.g.B[k][tn4 + 64];
                float av[8] = {af0.x, af0.y, af0.z, af0.w, af1.x, af1.y, af1.z, af1.w};
                float bw[8] = {bf0.x, bf0.y, bf0.z, bf0.w, bf1.x, bf1.y, bf1.z, bf1.w};
                #pragma unroll
                for (int i = 0; i < 8; i++)
                    #pragma unroll
                    for (int j = 0; j < 8; j++)
                        acc[i][j] = fmaf(av[i], bw[j], acc[i][j]);
            }
        }

        #pragma unroll
        for (int j = 0; j < 8; j++) {
            int col = tn4 + ((j < 4) ? j : 60 + j);
            int r = rt + col;
            bool valid = (r < segEnd);
            float iv = inv[valid ? r : 0];
            #pragma unroll
            for (int i = 0; i < 8; i++) {
                float v = acc[i][j] * iv;
                if (valid && v > bv[i]) { bv[i] = v; bi[i] = r; }
            }
        }
    }

    __syncthreads();
    #pragma unroll
    for (int i = 0; i < 8; i++) {
        int row = tm4 + ((i < 4) ? i : 60 + i);
        sm.red.rv[row][t >> 4] = bv[i];
        sm.red.ri[row][t >> 4] = bi[i];
    }
    __syncthreads();
    if (t < MT) {
        float v = sm.red.rv[t][0];
        int idx = sm.red.ri[t][0];
        #pragma unroll
        for (int j = 1; j < 16; j++) {
            float v2 = sm.red.rv[t][j];
            int i2 = sm.red.ri[t][j];
            if (v2 > v || (v2 == v && i2 < idx)) { v = v2; idx = i2; }
        }
        int gi = itile * MT + t;
        if (gi < NP) {
            size_t o = ((size_t)n * NSEG + seg) * NP + gi;
            bestv[o] = v;
            besti[o] = idx;
        }
    }
}

__global__ __launch_bounds__(256) void reduce_flow_kernel(
    const float* __restrict__ bestv, const int* __restrict__ besti,
    float* __restrict__ flowh, float* __restrict__ floww)
{
    int t = blockIdx.x * 256 + threadIdx.x;
    if (t >= NITEM * NP) return;
    int n = t / NP;
    int i = t - n * NP;
    const float* bvp = bestv + (size_t)n * NSEG * NP;
    const int* bip = besti + (size_t)n * NSEG * NP;
    float v = bvp[i];
    int idx = bip[i];
    #pragma unroll
    for (int s = 1; s < NSEG; s++) {
        float v2 = bvp[s * NP + i];
        int i2 = bip[s * NP + i];
        if (v2 > v || (v2 == v && i2 < idx)) { v = v2; idx = i2; }
    }
    int yi = i / HP, xi = i - yi * HP;
    int yr = idx / HP, xr = idx - yr * HP;
    flowh[t] = (float)(yr - yi);
    floww[t] = (float)(xr - xi);
}

// ---------------- Kernel 5: expand to 9 shifted copies, channel-interleaved ----------------
__global__ __launch_bounds__(256) void expand_kernel(
    const float* __restrict__ flowh, const float* __restrict__ floww,
    float* __restrict__ out)
{
    int t = blockIdx.x * 256 + threadIdx.x;
    const int total = NITEM * 18 * HW;
    if (t >= total) return;
    int x = t % W;
    int y = (t / W) % H;
    int chn = (t / HW) % 18;
    int n = t / (18 * HW);
    int k = chn >> 1;
    int b = chn & 1;
    int is = k / 3, js = k - is * 3;
    int ys = y - is, xs = x - js;
    float val = 0.f;
    if (ys >= 0 && ys < HP && xs >= 0 && xs < HP) {
        int src = n * NP + ys * HP + xs;
        val = b ? floww[src] : flowh[src];
    }
    out[t] = val;
}

// ---------------- Launch ----------------
extern "C" void kernel_launch(void* const* d_in, const int* in_sizes, int n_in,
                              void* d_out, int out_size, void* d_ws, size_t ws_size,
                              hipStream_t stream) {
    (void)in_sizes; (void)n_in; (void)out_size;
    const float* f1 = (const float*)d_in[0];
    const float* f2 = (const float*)d_in[1];
    float* ws = (float*)d_ws;

    // common carve
    float* fiN  = ws;                                  // 2*9216*64
    float* frN  = fiN + NITEM * HW * C;                // 2*9216*64
    float* ssn  = frN + NITEM * HW * C;                // 2*9216
    float* invn = ssn + NITEM * HW;                    // 2*8836
    float* after = invn + NITEM * NP;

    // factored-path carve
    float* s1    = after;                              // 2*960*9216
    float* pbv   = s1 + (size_t)NITEM * S1ROWS * HW;   // 2*94*8836
    int*   pbi   = (int*)(pbv + (size_t)NITEM * HP * NP);
    float* flowhF = (float*)(pbi + (size_t)NITEM * HP * NP);
    float* flowwF = flowhF + NITEM * NP;
    size_t factored_words = (size_t)(flowwF + NITEM * NP - ws);
    bool use_factored = ws_size >= factored_words * sizeof(float);

    {
        int nthreads = 2 * NITEM * HW;
        normalize_kernel<<<(nthreads + 255) / 256, 256, 0, stream>>>(f1, f2, fiN, frN, ssn);
    }
    {
        int nthreads = NITEM * NP;
        refnorm_kernel<<<(nthreads + 255) / 256, 256, 0, stream>>>(ssn, invn);
    }

    if (use_factored) {
        for (int b = 0; b < NBAND; b++) {
            int ry0 = b * BRY;
            int bryb = (HP - ry0 < BRY) ? (HP - ry0) : BRY;
            dim3 ga(NPT, NQT, NITEM);
            gemmS1_kernel<<<ga, 256, 0, stream>>>(fiN, frN, s1, ry0);
            dim3 gb(bryb, NIT, NITEM);
            pass2_kernel<<<gb, 256, 0, stream>>>(s1, invn, pbv, pbi, ry0);
        }
        {
            int nthreads = NITEM * NP;
            reduce94_kernel<<<(nthreads + 255) / 256, 256, 0, stream>>>(pbv, pbi, flowhF, flowwF);
            expand_kernel<<<(NITEM * 18 * HW + 255) / 256, 256, 0, stream>>>(flowhF, flowwF, (float*)d_out);
        }
    } else {
        // fallback carve (fits ~10 MB)
        float* bestv = after;                               // 2*8*8836
        int*   besti = (int*)(bestv + NITEM * NSEG * NP);
        float* flowh = (float*)(besti + NITEM * NSEG * NP);
        float* floww = flowh + NITEM * NP;
        dim3 grid(NMTILE, NSEG, NITEM);
        corr_kernel<<<grid, 256, 0, stream>>>(fiN, frN, invn, bestv, besti);
        int nthreads = NITEM * NP;
        reduce_flow_kernel<<<(nthreads + 255) / 256, 256, 0, stream>>>(bestv, besti, flowh, floww);
        expand_kernel<<<(NITEM * 18 * HW + 255) / 256, 256, 0, stream>>>(flowh, floww, (float*)d_out);
    }
}

// Round 9
// 1010.392 us; speedup vs baseline: 1.7234x; 1.7234x over previous
//
#include <hip/hip_runtime.h>
#include <math.h>

// Problem constants (N=2, C=64, H=96, W=96, PATCH=3)
static constexpr int NITEM = 2;
static constexpr int C = 64;
static constexpr int H = 96;
static constexpr int W = 96;
static constexpr int HW = H * W;         // 9216 pixels
static constexpr int HP = 94;            // H - 3 + 1
static constexpr int NP = HP * HP;       // 8836 patch positions

// ---- factored-path constants ----
static constexpr int BRY = 8;                       // ref patch-rows per band
static constexpr int NBAND = (HP + BRY - 1) / BRY;  // 12
static constexpr int PYB = BRY + 2;                 // pixel rows per band = 10
static constexpr int PROWS = PYB * W;               // 960 P rows per item per band
static constexpr int TSP = 128;                     // P tile (no halo needed)
static constexpr int NPT = HW / TSP;                // 72 p-tiles (exact)
static constexpr int NQT = (PROWS + TSP - 1) / TSP; // 8 q-tiles
static constexpr int ITILE = 256;                   // i's per pass2 block (1 per thread)
static constexpr int NIT = (NP + ITILE - 1) / ITILE; // 35
static constexpr int PAD = 132;                     // LDS row pad

// ---- fallback (R4 direct) constants ----
static constexpr int NSEG = 8;
static constexpr int SEGLEN = (NP + NSEG - 1) / NSEG; // 1105
static constexpr int MT = 128;
static constexpr int NT = 128;
static constexpr int KC = 16;
static constexpr int LDP = MT + 4;
static constexpr int NMTILE = (NP + MT - 1) / MT;   // 70

// ---------------- Kernel 1: per-pixel channel L2 normalize + NCHW->NHWC ----------------
__global__ __launch_bounds__(256) void normalize_kernel(
    const float* __restrict__ f1, const float* __restrict__ f2,
    float* __restrict__ fiN, float* __restrict__ frN, float* __restrict__ ssn)
{
    int t = blockIdx.x * 256 + threadIdx.x;
    const int perTensor = NITEM * HW;
    if (t >= 2 * perTensor) return;
    int which = t / perTensor;
    int p = t - which * perTensor;
    int n = p / HW;
    int pix = p - n * HW;
    const float* src = (which ? f2 : f1) + (size_t)n * C * HW + pix;
    float s = 0.f;
    #pragma unroll
    for (int c = 0; c < C; c++) {
        float v = src[c * HW];
        s = fmaf(v, v, s);
    }
    float norm = sqrtf(s);
    float scale = 1.0f / fmaxf(norm, 1e-12f);
    float* dst = (which ? frN : fiN) + (size_t)p * C;
    #pragma unroll
    for (int c = 0; c < C; c++) {
        dst[c] = src[c * HW] * scale;
    }
    if (which) ssn[p] = s * scale * scale;
}

// ---------------- Kernel 2: ref patch inverse norms ----------------
__global__ __launch_bounds__(256) void refnorm_kernel(
    const float* __restrict__ ssn, float* __restrict__ invn)
{
    int t = blockIdx.x * 256 + threadIdx.x;
    if (t >= NITEM * NP) return;
    int n = t / NP;
    int r = t - n * NP;
    int yr = r / HP, xr = r - yr * HP;
    const float* s = ssn + n * HW;
    float acc = 0.f;
    #pragma unroll
    for (int dy = 0; dy < 3; dy++)
        #pragma unroll
        for (int dx = 0; dx < 3; dx++)
            acc += s[(yr + dy) * W + (xr + dx)];
    invn[t] = 1.0f / (sqrtf(acc) + 1e-5f);
}

// ================= FACTORED PATH =================
// Kernel A: band GEMM writing RAW pixel-correlation P[q][p] (K=64), no epilogue.
// P[qL][p] = sum_c frN[ry0*W + qL][c] * fiN[p][c].
__global__ __launch_bounds__(256) void gemmP_kernel(
    const float* __restrict__ fiN, const float* __restrict__ frN,
    float* __restrict__ pmat, int ry0)
{
    __shared__ struct { float Aq[C][PAD]; float Bp[C][PAD]; } sm;  // 67584 B

    const int t = threadIdx.x;
    const int pt0 = blockIdx.x * TSP;    // global pixel col base (128-aligned)
    const int qt0 = blockIdx.y * TSP;    // band-local q base
    const int n = blockIdx.z;

    const float* fa = frN + (size_t)n * HW * C;  // q side (ref)
    const float* fb = fiN + (size_t)n * HW * C;  // p side (input)

    // ---- stage panels (monolithic K=64)
    {
        const int lrow = t >> 2;
        const int c0 = (t & 3) * 16;
        #pragma unroll
        for (int rr = 0; rr < 2; rr++) {
            int m = lrow + rr * 64;
            int qpix = ry0 * W + qt0 + m; if (qpix > HW - 1) qpix = HW - 1;
            int ppix = pt0 + m;           if (ppix > HW - 1) ppix = HW - 1;
            const float* qa = fa + (size_t)qpix * C + c0;
            const float* pb = fb + (size_t)ppix * C + c0;
            #pragma unroll
            for (int u = 0; u < 4; u++) {
                float4 va = *(const float4*)(qa + 4 * u);
                float4 vb = *(const float4*)(pb + 4 * u);
                sm.Aq[c0 + 4 * u + 0][m] = va.x; sm.Aq[c0 + 4 * u + 1][m] = va.y;
                sm.Aq[c0 + 4 * u + 2][m] = va.z; sm.Aq[c0 + 4 * u + 3][m] = va.w;
                sm.Bp[c0 + 4 * u + 0][m] = vb.x; sm.Bp[c0 + 4 * u + 1][m] = vb.y;
                sm.Bp[c0 + 4 * u + 2][m] = vb.z; sm.Bp[c0 + 4 * u + 3][m] = vb.w;
            }
        }
    }
    __syncthreads();

    // ---- 128x128 GEMM, K=64. q slow across lanes (broadcast), p fast (coalesced stores).
    const int tmq = (t >> 4) * 4;   // q fragment base
    const int tnp = (t & 15) * 4;   // p fragment base
    float acc[8][8];
    #pragma unroll
    for (int i = 0; i < 8; i++)
        #pragma unroll
        for (int j = 0; j < 8; j++) acc[i][j] = 0.f;

    #pragma unroll 4
    for (int k = 0; k < C; k++) {
        float4 af0 = *(const float4*)&sm.Aq[k][tmq];
        float4 af1 = *(const float4*)&sm.Aq[k][tmq + 64];
        float4 bf0 = *(const float4*)&sm.Bp[k][tnp];
        float4 bf1 = *(const float4*)&sm.Bp[k][tnp + 64];
        float av[8] = {af0.x, af0.y, af0.z, af0.w, af1.x, af1.y, af1.z, af1.w};
        float bw[8] = {bf0.x, bf0.y, bf0.z, bf0.w, bf1.x, bf1.y, bf1.z, bf1.w};
        #pragma unroll
        for (int i = 0; i < 8; i++)
            #pragma unroll
            for (int j = 0; j < 8; j++)
                acc[i][j] = fmaf(av[i], bw[j], acc[i][j]);
    }

    // ---- direct register->global stores (two float4 per q-row), no LDS round trip
    float* pn = pmat + (size_t)n * PROWS * HW;
    #pragma unroll
    for (int i = 0; i < 8; i++) {
        int qq = tmq + ((i < 4) ? i : 60 + i);
        int qL = qt0 + qq;
        if (qL < PROWS) {
            float* row = pn + (size_t)qL * HW + pt0;
            *(float4*)(row + tnp)      = make_float4(acc[i][0], acc[i][1], acc[i][2], acc[i][3]);
            *(float4*)(row + tnp + 64) = make_float4(acc[i][4], acc[i][5], acc[i][6], acc[i][7]);
        }
    }
}

// Kernel B: full 3x3 DIAGONAL sum from raw P + patch-norm scale + per-ry argmax.
// term(dy,dx) = P[(ryL+dy)*W + rx + dx][ppix + dy*W + dx]
//   -> flat offset from bdy base: rx*HW + dx*(HW+1)   (dx shifts row AND col!)
// Grouping ((dx0+dx1)+dx2) per dy, then ((s0+s1)+s2)*inv — bit-identical to R6 S1 path.
__global__ __launch_bounds__(256) void pass2_kernel(
    const float* __restrict__ pmat, const float* __restrict__ invn,
    float* __restrict__ pbv, int* __restrict__ pbi, int ry0)
{
    const int t = threadIdx.x;
    const int ryL = blockIdx.x;          // band-local ref patch-row
    const int ry = ry0 + ryL;            // global ref patch-row
    const int n = blockIdx.z;
    const int i = blockIdx.y * ITILE + t;
    if (i >= NP) return;

    const float* pn = pmat + (size_t)n * PROWS * HW;
    const float* inv = invn + (size_t)n * NP + ry * HP;
    const int rBase = ry * HP;

    int iy = i / HP, ix = i - iy * HP;
    int ppix = iy * W + ix;
    // dy bases: row (ryL+dy)*W, col ppix + dy*W
    const float* b0 = pn + (size_t)(ryL * W) * HW + ppix;
    const float* b1 = b0 + (size_t)W * HW + W;
    const float* b2 = b1 + (size_t)W * HW + W;
    const size_t D = (size_t)HW + 1;     // diagonal stride (+1 row, +1 col)

    float bv = -INFINITY;
    int brx = 0;
    #pragma unroll 2
    for (int rx = 0; rx < HP; rx++) {
        size_t o = (size_t)rx * HW;
        float s0 = (b0[o] + b0[o + D]) + b0[o + 2 * D];
        float s1 = (b1[o] + b1[o + D]) + b1[o + 2 * D];
        float s2 = (b2[o] + b2[o + D]) + b2[o + 2 * D];
        float v = ((s0 + s1) + s2) * inv[rx];
        if (v > bv) { bv = v; brx = rx; }
    }
    size_t o = ((size_t)n * HP + ry) * NP + i;
    pbv[o] = bv;
    pbi[o] = rBase + brx;
}

// Reduce over 94 ry partials -> flow (lexicographic: first global max)
__global__ __launch_bounds__(256) void reduce94_kernel(
    const float* __restrict__ pbv, const int* __restrict__ pbi,
    float* __restrict__ flowh, float* __restrict__ floww)
{
    int t = blockIdx.x * 256 + threadIdx.x;
    if (t >= NITEM * NP) return;
    int n = t / NP;
    int i = t - n * NP;
    const float* bvp = pbv + (size_t)n * HP * NP;
    const int* bip = pbi + (size_t)n * HP * NP;
    float v = bvp[i];
    int idx = bip[i];
    for (int s = 1; s < HP; s++) {
        float v2 = bvp[(size_t)s * NP + i];
        int i2 = bip[(size_t)s * NP + i];
        if (v2 > v || (v2 == v && i2 < idx)) { v = v2; idx = i2; }
    }
    int yi = i / HP, xi = i - yi * HP;
    int yr = idx / HP, xr = idx - yr * HP;
    flowh[t] = (float)(yr - yi);
    floww[t] = (float)(xr - xi);
}

// ================= FALLBACK PATH (R4 direct, proven) =================
__global__ __launch_bounds__(256) void corr_kernel(
    const float* __restrict__ fiN, const float* __restrict__ frN,
    const float* __restrict__ invn,
    float* __restrict__ bestv, int* __restrict__ besti)
{
    __shared__ union SM {
        struct { float A[KC][LDP]; float B[KC][LDP]; } g;
        struct { float rv[MT][16]; int ri[MT][16]; } red;
    } sm;

    const int t = threadIdx.x;
    const int itile = blockIdx.x;
    const int seg = blockIdx.y;
    const int n = blockIdx.z;

    const float* fa = fiN + (size_t)n * HW * C;
    const float* fb = frN + (size_t)n * HW * C;
    const float* inv = invn + (size_t)n * NP;

    const int lrow = t >> 2;
    const int lc = (t & 3) * 4;

    int ia0 = itile * MT + lrow;      if (ia0 > NP - 1) ia0 = NP - 1;
    int ia1 = itile * MT + lrow + 64; if (ia1 > NP - 1) ia1 = NP - 1;
    const int ay0 = ia0 / HP, ax0 = ia0 - ay0 * HP;
    const int ay1 = ia1 / HP, ax1 = ia1 - ay1 * HP;
    const int aoff0 = (ay0 * W + ax0) * C;
    const int aoff1 = (ay1 * W + ax1) * C;

    const int tm4 = (t & 15) * 4;
    const int tn4 = (t >> 4) * 4;

    const int segStart = seg * SEGLEN;
    const int segEnd = (segStart + SEGLEN < NP) ? segStart + SEGLEN : NP;

    float bv[8];
    int bi[8];
    #pragma unroll
    for (int i = 0; i < 8; i++) { bv[i] = -INFINITY; bi[i] = 0; }

    for (int rt = segStart; rt < segEnd; rt += NT) {
        int ib0 = rt + lrow;      if (ib0 > NP - 1) ib0 = NP - 1;
        int ib1 = rt + lrow + 64; if (ib1 > NP - 1) ib1 = NP - 1;
        const int by0 = ib0 / HP, bx0 = ib0 - by0 * HP;
        const int by1 = ib1 / HP, bx1 = ib1 - by1 * HP;
        const int boff0 = (by0 * W + bx0) * C;
        const int boff1 = (by1 * W + bx1) * C;

        float acc[8][8];
        #pragma unroll
        for (int i = 0; i < 8; i++)
            #pragma unroll
            for (int j = 0; j < 8; j++) acc[i][j] = 0.f;

        float4 a0 = *(const float4*)(fa + aoff0 + lc);
        float4 a1 = *(const float4*)(fa + aoff1 + lc);
        float4 b0 = *(const float4*)(fb + boff0 + lc);
        float4 b1 = *(const float4*)(fb + boff1 + lc);

        #pragma unroll 1
        for (int ch = 0; ch < 36; ch++) {
            __syncthreads();
            sm.g.A[lc + 0][lrow] = a0.x; sm.g.A[lc + 1][lrow] = a0.y;
            sm.g.A[lc + 2][lrow] = a0.z; sm.g.A[lc + 3][lrow] = a0.w;
            sm.g.A[lc + 0][lrow + 64] = a1.x; sm.g.A[lc + 1][lrow + 64] = a1.y;
            sm.g.A[lc + 2][lrow + 64] = a1.z; sm.g.A[lc + 3][lrow + 64] = a1.w;
            sm.g.B[lc + 0][lrow] = b0.x; sm.g.B[lc + 1][lrow] = b0.y;
            sm.g.B[lc + 2][lrow] = b0.z; sm.g.B[lc + 3][lrow] = b0.w;
            sm.g.B[lc + 0][lrow + 64] = b1.x; sm.g.B[lc + 1][lrow + 64] = b1.y;
            sm.g.B[lc + 2][lrow + 64] = b1.z; sm.g.B[lc + 3][lrow + 64] = b1.w;
            __syncthreads();

            if (ch < 35) {
                const int chn = ch + 1;
                const int pp = chn >> 2;
                const int c0 = (chn & 3) << 4;
                const int dy = pp / 3, dx = pp - dy * 3;
                const int poff = (dy * W + dx) * C + c0 + lc;
                a0 = *(const float4*)(fa + aoff0 + poff);
                a1 = *(const float4*)(fa + aoff1 + poff);
                b0 = *(const float4*)(fb + boff0 + poff);
                b1 = *(const float4*)(fb + boff1 + poff);
            }

            #pragma unroll
            for (int k = 0; k < KC; k++) {
                float4 af0 = *(const float4*)&sm.g.A[k][tm4];
                float4 af1 = *(const float4*)&sm.g.A[k][tm4 + 64];
                float4 bf0 = *(const float4*)&sm.g.B[k][tn4];
                float4 bf1 = *(const float4*)&sm.g.B[k][tn4 + 64];
                float av[8] = {af0.x, af0.y, af0.z, af0.w, af1.x, af1.y, af1.z, af1.w};
                float bw[8] = {bf0.x, bf0.y, bf0.z, bf0.w, bf1.x, bf1.y, bf1.z, bf1.w};
                #pragma unroll
                for (int i = 0; i < 8; i++)
                    #pragma unroll
                    for (int j = 0; j < 8; j++)
                        acc[i][j] = fmaf(av[i], bw[j], acc[i][j]);
            }
        }

        #pragma unroll
        for (int j = 0; j < 8; j++) {
            int col = tn4 + ((j < 4) ? j : 60 + j);
            int r = rt + col;
            bool valid = (r < segEnd);
            float iv = inv[valid ? r : 0];
            #pragma unroll
            for (int i = 0; i < 8; i++) {
                float v = acc[i][j] * iv;
                if (valid && v > bv[i]) { bv[i] = v; bi[i] = r; }
            }
        }
    }

    __syncthreads();
    #pragma unroll
    for (int i = 0; i < 8; i++) {
        int row = tm4 + ((i < 4) ? i : 60 + i);
        sm.red.rv[row][t >> 4] = bv[i];
        sm.red.ri[row][t >> 4] = bi[i];
    }
    __syncthreads();
    if (t < MT) {
        float v = sm.red.rv[t][0];
        int idx = sm.red.ri[t][0];
        #pragma unroll
        for (int j = 1; j < 16; j++) {
            float v2 = sm.red.rv[t][j];
            int i2 = sm.red.ri[t][j];
            if (v2 > v || (v2 == v && i2 < idx)) { v = v2; idx = i2; }
        }
        int gi = itile * MT + t;
        if (gi < NP) {
            size_t o = ((size_t)n * NSEG + seg) * NP + gi;
            bestv[o] = v;
            besti[o] = idx;
        }
    }
}

__global__ __launch_bounds__(256) void reduce_flow_kernel(
    const float* __restrict__ bestv, const int* __restrict__ besti,
    float* __restrict__ flowh, float* __restrict__ floww)
{
    int t = blockIdx.x * 256 + threadIdx.x;
    if (t >= NITEM * NP) return;
    int n = t / NP;
    int i = t - n * NP;
    const float* bvp = bestv + (size_t)n * NSEG * NP;
    const int* bip = besti + (size_t)n * NSEG * NP;
    float v = bvp[i];
    int idx = bip[i];
    #pragma unroll
    for (int s = 1; s < NSEG; s++) {
        float v2 = bvp[s * NP + i];
        int i2 = bip[s * NP + i];
        if (v2 > v || (v2 == v && i2 < idx)) { v = v2; idx = i2; }
    }
    int yi = i / HP, xi = i - yi * HP;
    int yr = idx / HP, xr = idx - yr * HP;
    flowh[t] = (float)(yr - yi);
    floww[t] = (float)(xr - xi);
}

// ---------------- Kernel 5: expand to 9 shifted copies, channel-interleaved ----------------
__global__ __launch_bounds__(256) void expand_kernel(
    const float* __restrict__ flowh, const float* __restrict__ floww,
    float* __restrict__ out)
{
    int t = blockIdx.x * 256 + threadIdx.x;
    const int total = NITEM * 18 * HW;
    if (t >= total) return;
    int x = t % W;
    int y = (t / W) % H;
    int chn = (t / HW) % 18;
    int n = t / (18 * HW);
    int k = chn >> 1;
    int b = chn & 1;
    int is = k / 3, js = k - is * 3;
    int ys = y - is, xs = x - js;
    float val = 0.f;
    if (ys >= 0 && ys < HP && xs >= 0 && xs < HP) {
        int src = n * NP + ys * HP + xs;
        val = b ? floww[src] : flowh[src];
    }
    out[t] = val;
}

// ---------------- Launch ----------------
extern "C" void kernel_launch(void* const* d_in, const int* in_sizes, int n_in,
                              void* d_out, int out_size, void* d_ws, size_t ws_size,
                              hipStream_t stream) {
    (void)in_sizes; (void)n_in; (void)out_size;
    const float* f1 = (const float*)d_in[0];
    const float* f2 = (const float*)d_in[1];
    float* ws = (float*)d_ws;

    // common carve
    float* fiN  = ws;                                  // 2*9216*64
    float* frN  = fiN + NITEM * HW * C;                // 2*9216*64
    float* ssn  = frN + NITEM * HW * C;                // 2*9216
    float* invn = ssn + NITEM * HW;                    // 2*8836
    float* after = invn + NITEM * NP;

    // factored-path carve (P buffer 64B-aligned)
    size_t afterOff = (size_t)(after - ws);
    afterOff = (afterOff + 63) & ~(size_t)63;
    float* pmat  = ws + afterOff;                      // 2*960*9216
    float* pbv   = pmat + (size_t)NITEM * PROWS * HW;  // 2*94*8836
    int*   pbi   = (int*)(pbv + (size_t)NITEM * HP * NP);
    float* flowhF = (float*)(pbi + (size_t)NITEM * HP * NP);
    float* flowwF = flowhF + NITEM * NP;
    size_t factored_words = (size_t)(flowwF + NITEM * NP - ws);
    bool use_factored = ws_size >= factored_words * sizeof(float);

    {
        int nthreads = 2 * NITEM * HW;
        normalize_kernel<<<(nthreads + 255) / 256, 256, 0, stream>>>(f1, f2, fiN, frN, ssn);
    }
    {
        int nthreads = NITEM * NP;
        refnorm_kernel<<<(nthreads + 255) / 256, 256, 0, stream>>>(ssn, invn);
    }

    if (use_factored) {
        for (int b = 0; b < NBAND; b++) {
            int ry0 = b * BRY;
            int bryb = (HP - ry0 < BRY) ? (HP - ry0) : BRY;
            dim3 ga(NPT, NQT, NITEM);
            gemmP_kernel<<<ga, 256, 0, stream>>>(fiN, frN, pmat, ry0);
            dim3 gb(bryb, NIT, NITEM);
            pass2_kernel<<<gb, 256, 0, stream>>>(pmat, invn, pbv, pbi, ry0);
        }
        {
            int nthreads = NITEM * NP;
            reduce94_kernel<<<(nthreads + 255) / 256, 256, 0, stream>>>(pbv, pbi, flowhF, flowwF);
            expand_kernel<<<(NITEM * 18 * HW + 255) / 256, 256, 0, stream>>>(flowhF, flowwF, (float*)d_out);
        }
    } else {
        // fallback carve (fits ~10 MB)
        float* bestv = after;                               // 2*8*8836
        int*   besti = (int*)(bestv + NITEM * NSEG * NP);
        float* flowh = (float*)(besti + NITEM * NSEG * NP);
        float* floww = flowh + NITEM * NP;
        dim3 grid(NMTILE, NSEG, NITEM);
        corr_kernel<<<grid, 256, 0, stream>>>(fiN, frN, invn, bestv, besti);
        int nthreads = NITEM * NP;
        reduce_flow_kernel<<<(nthreads + 255) / 256, 256, 0, stream>>>(bestv, besti, flowh, floww);
        expand_kernel<<<(NITEM * 18 * HW + 255) / 256, 256, 0, stream>>>(flowh, floww, (float*)d_out);
    }
}

// Round 10
// 1000.919 us; speedup vs baseline: 1.7397x; 1.0095x over previous
//
#include <hip/hip_runtime.h>
#include <math.h>

// Problem constants (N=2, C=64, H=96, W=96, PATCH=3)
static constexpr int NITEM = 2;
static constexpr int C = 64;
static constexpr int H = 96;
static constexpr int W = 96;
static constexpr int HW = H * W;         // 9216 pixels
static constexpr int HP = 94;            // H - 3 + 1
static constexpr int NP = HP * HP;       // 8836 patch positions

// ---- factored-path constants ----
static constexpr int BRY = 8;                       // ref patch-rows per band
static constexpr int NBAND = (HP + BRY - 1) / BRY;  // 12
static constexpr int PYB = BRY + 2;                 // pixel rows per band = 10
static constexpr int PROWS = PYB * W;               // 960 P rows per item per band
static constexpr int TSP = 128;                     // P tile
static constexpr int NPT = HW / TSP;                // 72 p-tiles (exact)
static constexpr int NQT = (PROWS + TSP - 1) / TSP; // 8 q-tiles
static constexpr int ITILE = 256;                   // i's per pass2 block (1 per thread)
static constexpr int NIT = (NP + ITILE - 1) / ITILE; // 35
static constexpr int PAD = 132;                     // LDS row pad

// ---- fallback (R4 direct) constants ----
static constexpr int NSEG = 8;
static constexpr int SEGLEN = (NP + NSEG - 1) / NSEG; // 1105
static constexpr int MT = 128;
static constexpr int NT = 128;
static constexpr int KC = 16;
static constexpr int LDP = MT + 4;
static constexpr int NMTILE = (NP + MT - 1) / MT;   // 70

// ---------------- Kernel 1: per-pixel channel L2 normalize + NCHW->NHWC ----------------
__global__ __launch_bounds__(256) void normalize_kernel(
    const float* __restrict__ f1, const float* __restrict__ f2,
    float* __restrict__ fiN, float* __restrict__ frN, float* __restrict__ ssn)
{
    int t = blockIdx.x * 256 + threadIdx.x;
    const int perTensor = NITEM * HW;
    if (t >= 2 * perTensor) return;
    int which = t / perTensor;
    int p = t - which * perTensor;
    int n = p / HW;
    int pix = p - n * HW;
    const float* src = (which ? f2 : f1) + (size_t)n * C * HW + pix;
    float s = 0.f;
    #pragma unroll
    for (int c = 0; c < C; c++) {
        float v = src[c * HW];
        s = fmaf(v, v, s);
    }
    float norm = sqrtf(s);
    float scale = 1.0f / fmaxf(norm, 1e-12f);
    float* dst = (which ? frN : fiN) + (size_t)p * C;
    #pragma unroll
    for (int c = 0; c < C; c++) {
        dst[c] = src[c * HW] * scale;
    }
    if (which) ssn[p] = s * scale * scale;
}

// ---------------- Kernel 2: ref patch inverse norms ----------------
__global__ __launch_bounds__(256) void refnorm_kernel(
    const float* __restrict__ ssn, float* __restrict__ invn)
{
    int t = blockIdx.x * 256 + threadIdx.x;
    if (t >= NITEM * NP) return;
    int n = t / NP;
    int r = t - n * NP;
    int yr = r / HP, xr = r - yr * HP;
    const float* s = ssn + n * HW;
    float acc = 0.f;
    #pragma unroll
    for (int dy = 0; dy < 3; dy++)
        #pragma unroll
        for (int dx = 0; dx < 3; dx++)
            acc += s[(yr + dy) * W + (xr + dx)];
    invn[t] = 1.0f / (sqrtf(acc) + 1e-5f);
}

// ================= FACTORED PATH =================
// Kernel A: band GEMM writing RAW pixel-correlation P[q][p] (K=64), no epilogue.
// P[qL][p] = sum_c frN[ry0*W + qL][c] * fiN[p][c].
// Staging channel map: c0=(t&3)*4, channels c0+16u+j -> write bank =
// (16*(q&1)+4j+lrow) mod 32 = 2-way max (free). The old c0=(t&3)*16 map was
// q-independent in bank -> 4-way conflict on every staging write (22% of cycles).
__global__ __launch_bounds__(256) void gemmP_kernel(
    const float* __restrict__ fiN, const float* __restrict__ frN,
    float* __restrict__ pmat, int ry0)
{
    __shared__ struct { float Aq[C][PAD]; float Bp[C][PAD]; } sm;  // 67584 B

    const int t = threadIdx.x;
    const int pt0 = blockIdx.x * TSP;    // global pixel col base (128-aligned)
    const int qt0 = blockIdx.y * TSP;    // band-local q base
    const int n = blockIdx.z;

    const float* fa = frN + (size_t)n * HW * C;  // q side (ref)
    const float* fb = fiN + (size_t)n * HW * C;  // p side (input)

    // ---- stage panels (monolithic K=64), conflict-free write pattern
    {
        const int lrow = t >> 2;
        const int c0 = (t & 3) * 4;     // channel base; channels c0 + 16u + j
        #pragma unroll
        for (int rr = 0; rr < 2; rr++) {
            int m = lrow + rr * 64;
            int qpix = ry0 * W + qt0 + m; if (qpix > HW - 1) qpix = HW - 1;
            int ppix = pt0 + m;           if (ppix > HW - 1) ppix = HW - 1;
            const float* qa = fa + (size_t)qpix * C + c0;
            const float* pb = fb + (size_t)ppix * C + c0;
            #pragma unroll
            for (int u = 0; u < 4; u++) {
                float4 va = *(const float4*)(qa + 16 * u);
                float4 vb = *(const float4*)(pb + 16 * u);
                int cc = c0 + 16 * u;
                sm.Aq[cc + 0][m] = va.x; sm.Aq[cc + 1][m] = va.y;
                sm.Aq[cc + 2][m] = va.z; sm.Aq[cc + 3][m] = va.w;
                sm.Bp[cc + 0][m] = vb.x; sm.Bp[cc + 1][m] = vb.y;
                sm.Bp[cc + 2][m] = vb.z; sm.Bp[cc + 3][m] = vb.w;
            }
        }
    }
    __syncthreads();

    // ---- 128x128 GEMM, K=64. q slow across lanes (broadcast), p fast (coalesced stores).
    const int tmq = (t >> 4) * 4;   // q fragment base
    const int tnp = (t & 15) * 4;   // p fragment base
    float acc[8][8];
    #pragma unroll
    for (int i = 0; i < 8; i++)
        #pragma unroll
        for (int j = 0; j < 8; j++) acc[i][j] = 0.f;

    #pragma unroll 4
    for (int k = 0; k < C; k++) {
        float4 af0 = *(const float4*)&sm.Aq[k][tmq];
        float4 af1 = *(const float4*)&sm.Aq[k][tmq + 64];
        float4 bf0 = *(const float4*)&sm.Bp[k][tnp];
        float4 bf1 = *(const float4*)&sm.Bp[k][tnp + 64];
        float av[8] = {af0.x, af0.y, af0.z, af0.w, af1.x, af1.y, af1.z, af1.w};
        float bw[8] = {bf0.x, bf0.y, bf0.z, bf0.w, bf1.x, bf1.y, bf1.z, bf1.w};
        #pragma unroll
        for (int i = 0; i < 8; i++)
            #pragma unroll
            for (int j = 0; j < 8; j++)
                acc[i][j] = fmaf(av[i], bw[j], acc[i][j]);
    }

    // ---- direct register->global stores (two float4 per q-row), no LDS round trip
    float* pn = pmat + (size_t)n * PROWS * HW;
    #pragma unroll
    for (int i = 0; i < 8; i++) {
        int qq = tmq + ((i < 4) ? i : 60 + i);
        int qL = qt0 + qq;
        if (qL < PROWS) {
            float* row = pn + (size_t)qL * HW + pt0;
            *(float4*)(row + tnp)      = make_float4(acc[i][0], acc[i][1], acc[i][2], acc[i][3]);
            *(float4*)(row + tnp + 64) = make_float4(acc[i][4], acc[i][5], acc[i][6], acc[i][7]);
        }
    }
}

// Kernel B: full 3x3 DIAGONAL sum from raw P + patch-norm scale + per-ry argmax.
// term(dy,dx) = P[(ryL+dy)*W + rx + dx][ppix + dy*W + dx]
//   -> flat offset from b_dy base: rx*HW + dx*(HW+1)  (dx shifts row AND col)
__global__ __launch_bounds__(256) void pass2_kernel(
    const float* __restrict__ pmat, const float* __restrict__ invn,
    float* __restrict__ pbv, int* __restrict__ pbi, int ry0)
{
    const int t = threadIdx.x;
    const int ryL = blockIdx.x;          // band-local ref patch-row
    const int ry = ry0 + ryL;            // global ref patch-row
    const int n = blockIdx.z;
    const int i = blockIdx.y * ITILE + t;
    if (i >= NP) return;

    const float* pn = pmat + (size_t)n * PROWS * HW;
    const float* inv = invn + (size_t)n * NP + ry * HP;
    const int rBase = ry * HP;

    int iy = i / HP, ix = i - iy * HP;
    int ppix = iy * W + ix;
    const float* b0 = pn + (size_t)(ryL * W) * HW + ppix;
    const float* b1 = b0 + (size_t)W * HW + W;
    const float* b2 = b1 + (size_t)W * HW + W;
    const size_t D = (size_t)HW + 1;     // diagonal stride (+1 row, +1 col)

    float bv = -INFINITY;
    int brx = 0;
    #pragma unroll 2
    for (int rx = 0; rx < HP; rx++) {
        size_t o = (size_t)rx * HW;
        float s0 = (b0[o] + b0[o + D]) + b0[o + 2 * D];
        float s1 = (b1[o] + b1[o + D]) + b1[o + 2 * D];
        float s2 = (b2[o] + b2[o + D]) + b2[o + 2 * D];
        float v = ((s0 + s1) + s2) * inv[rx];
        if (v > bv) { bv = v; brx = rx; }
    }
    size_t o = ((size_t)n * HP + ry) * NP + i;
    pbv[o] = bv;
    pbi[o] = rBase + brx;
}

// Reduce over 94 ry partials -> flow (lexicographic: first global max)
__global__ __launch_bounds__(256) void reduce94_kernel(
    const float* __restrict__ pbv, const int* __restrict__ pbi,
    float* __restrict__ flowh, float* __restrict__ floww)
{
    int t = blockIdx.x * 256 + threadIdx.x;
    if (t >= NITEM * NP) return;
    int n = t / NP;
    int i = t - n * NP;
    const float* bvp = pbv + (size_t)n * HP * NP;
    const int* bip = pbi + (size_t)n * HP * NP;
    float v = bvp[i];
    int idx = bip[i];
    for (int s = 1; s < HP; s++) {
        float v2 = bvp[(size_t)s * NP + i];
        int i2 = bip[(size_t)s * NP + i];
        if (v2 > v || (v2 == v && i2 < idx)) { v = v2; idx = i2; }
    }
    int yi = i / HP, xi = i - yi * HP;
    int yr = idx / HP, xr = idx - yr * HP;
    flowh[t] = (float)(yr - yi);
    floww[t] = (float)(xr - xi);
}

// ================= FALLBACK PATH (R4 direct, proven) =================
__global__ __launch_bounds__(256) void corr_kernel(
    const float* __restrict__ fiN, const float* __restrict__ frN,
    const float* __restrict__ invn,
    float* __restrict__ bestv, int* __restrict__ besti)
{
    __shared__ union SM {
        struct { float A[KC][LDP]; float B[KC][LDP]; } g;
        struct { float rv[MT][16]; int ri[MT][16]; } red;
    } sm;

    const int t = threadIdx.x;
    const int itile = blockIdx.x;
    const int seg = blockIdx.y;
    const int n = blockIdx.z;

    const float* fa = fiN + (size_t)n * HW * C;
    const float* fb = frN + (size_t)n * HW * C;
    const float* inv = invn + (size_t)n * NP;

    const int lrow = t >> 2;
    const int lc = (t & 3) * 4;

    int ia0 = itile * MT + lrow;      if (ia0 > NP - 1) ia0 = NP - 1;
    int ia1 = itile * MT + lrow + 64; if (ia1 > NP - 1) ia1 = NP - 1;
    const int ay0 = ia0 / HP, ax0 = ia0 - ay0 * HP;
    const int ay1 = ia1 / HP, ax1 = ia1 - ay1 * HP;
    const int aoff0 = (ay0 * W + ax0) * C;
    const int aoff1 = (ay1 * W + ax1) * C;

    const int tm4 = (t & 15) * 4;
    const int tn4 = (t >> 4) * 4;

    const int segStart = seg * SEGLEN;
    const int segEnd = (segStart + SEGLEN < NP) ? segStart + SEGLEN : NP;

    float bv[8];
    int bi[8];
    #pragma unroll
    for (int i = 0; i < 8; i++) { bv[i] = -INFINITY; bi[i] = 0; }

    for (int rt = segStart; rt < segEnd; rt += NT) {
        int ib0 = rt + lrow;      if (ib0 > NP - 1) ib0 = NP - 1;
        int ib1 = rt + lrow + 64; if (ib1 > NP - 1) ib1 = NP - 1;
        const int by0 = ib0 / HP, bx0 = ib0 - by0 * HP;
        const int by1 = ib1 / HP, bx1 = ib1 - by1 * HP;
        const int boff0 = (by0 * W + bx0) * C;
        const int boff1 = (by1 * W + bx1) * C;

        float acc[8][8];
        #pragma unroll
        for (int i = 0; i < 8; i++)
            #pragma unroll
            for (int j = 0; j < 8; j++) acc[i][j] = 0.f;

        float4 a0 = *(const float4*)(fa + aoff0 + lc);
        float4 a1 = *(const float4*)(fa + aoff1 + lc);
        float4 b0 = *(const float4*)(fb + boff0 + lc);
        float4 b1 = *(const float4*)(fb + boff1 + lc);

        #pragma unroll 1
        for (int ch = 0; ch < 36; ch++) {
            __syncthreads();
            sm.g.A[lc + 0][lrow] = a0.x; sm.g.A[lc + 1][lrow] = a0.y;
            sm.g.A[lc + 2][lrow] = a0.z; sm.g.A[lc + 3][lrow] = a0.w;
            sm.g.A[lc + 0][lrow + 64] = a1.x; sm.g.A[lc + 1][lrow + 64] = a1.y;
            sm.g.A[lc + 2][lrow + 64] = a1.z; sm.g.A[lc + 3][lrow + 64] = a1.w;
            sm.g.B[lc + 0][lrow] = b0.x; sm.g.B[lc + 1][lrow] = b0.y;
            sm.g.B[lc + 2][lrow] = b0.z; sm.g.B[lc + 3][lrow] = b0.w;
            sm.g.B[lc + 0][lrow + 64] = b1.x; sm.g.B[lc + 1][lrow + 64] = b1.y;
            sm.g.B[lc + 2][lrow + 64] = b1.z; sm.g.B[lc + 3][lrow + 64] = b1.w;
            __syncthreads();

            if (ch < 35) {
                const int chn = ch + 1;
                const int pp = chn >> 2;
                const int c0 = (chn & 3) << 4;
                const int dy = pp / 3, dx = pp - dy * 3;
                const int poff = (dy * W + dx) * C + c0 + lc;
                a0 = *(const float4*)(fa + aoff0 + poff);
                a1 = *(const float4*)(fa + aoff1 + poff);
                b0 = *(const float4*)(fb + boff0 + poff);
                b1 = *(const float4*)(fb + boff1 + poff);
            }

            #pragma unroll
            for (int k = 0; k < KC; k++) {
                float4 af0 = *(const float4*)&sm.g.A[k][tm4];
                float4 af1 = *(const float4*)&sm.g.A[k][tm4 + 64];
                float4 bf0 = *(const float4*)&sm.g.B[k][tn4];
                float4 bf1 = *(const float4*)&sm.g.B[k][tn4 + 64];
                float av[8] = {af0.x, af0.y, af0.z, af0.w, af1.x, af1.y, af1.z, af1.w};
                float bw[8] = {bf0.x, bf0.y, bf0.z, bf0.w, bf1.x, bf1.y, bf1.z, bf1.w};
                #pragma unroll
                for (int i = 0; i < 8; i++)
                    #pragma unroll
                    for (int j = 0; j < 8; j++)
                        acc[i][j] = fmaf(av[i], bw[j], acc[i][j]);
            }
        }

        #pragma unroll
        for (int j = 0; j < 8; j++) {
            int col = tn4 + ((j < 4) ? j : 60 + j);
            int r = rt + col;
            bool valid = (r < segEnd);
            float iv = inv[valid ? r : 0];
            #pragma unroll
            for (int i = 0; i < 8; i++) {
                float v = acc[i][j] * iv;
                if (valid && v > bv[i]) { bv[i] = v; bi[i] = r; }
            }
        }
    }

    __syncthreads();
    #pragma unroll
    for (int i = 0; i < 8; i++) {
        int row = tm4 + ((i < 4) ? i : 60 + i);
        sm.red.rv[row][t >> 4] = bv[i];
        sm.red.ri[row][t >> 4] = bi[i];
    }
    __syncthreads();
    if (t < MT) {
        float v = sm.red.rv[t][0];
        int idx = sm.red.ri[t][0];
        #pragma unroll
        for (int j = 1; j < 16; j++) {
            float v2 = sm.red.rv[t][j];
            int i2 = sm.red.ri[t][j];
            if (v2 > v || (v2 == v && i2 < idx)) { v = v2; idx = i2; }
        }
        int gi = itile * MT + t;
        if (gi < NP) {
            size_t o = ((size_t)n * NSEG + seg) * NP + gi;
            bestv[o] = v;
            besti[o] = idx;
        }
    }
}

__global__ __launch_bounds__(256) void reduce_flow_kernel(
    const float* __restrict__ bestv, const int* __restrict__ besti,
    float* __restrict__ flowh, float* __restrict__ floww)
{
    int t = blockIdx.x * 256 + threadIdx.x;
    if (t >= NITEM * NP) return;
    int n = t / NP;
    int i = t - n * NP;
    const float* bvp = bestv + (size_t)n * NSEG * NP;
    const int* bip = besti + (size_t)n * NSEG * NP;
    float v = bvp[i];
    int idx = bip[i];
    #pragma unroll
    for (int s = 1; s < NSEG; s++) {
        float v2 = bvp[s * NP + i];
        int i2 = bip[s * NP + i];
        if (v2 > v || (v2 == v && i2 < idx)) { v = v2; idx = i2; }
    }
    int yi = i / HP, xi = i - yi * HP;
    int yr = idx / HP, xr = idx - yr * HP;
    flowh[t] = (float)(yr - yi);
    floww[t] = (float)(xr - xi);
}

// ---------------- Kernel 5: expand to 9 shifted copies, channel-interleaved ----------------
__global__ __launch_bounds__(256) void expand_kernel(
    const float* __restrict__ flowh, const float* __restrict__ floww,
    float* __restrict__ out)
{
    int t = blockIdx.x * 256 + threadIdx.x;
    const int total = NITEM * 18 * HW;
    if (t >= total) return;
    int x = t % W;
    int y = (t / W) % H;
    int chn = (t / HW) % 18;
    int n = t / (18 * HW);
    int k = chn >> 1;
    int b = chn & 1;
    int is = k / 3, js = k - is * 3;
    int ys = y - is, xs = x - js;
    float val = 0.f;
    if (ys >= 0 && ys < HP && xs >= 0 && xs < HP) {
        int src = n * NP + ys * HP + xs;
        val = b ? floww[src] : flowh[src];
    }
    out[t] = val;
}

// ---------------- Launch ----------------
extern "C" void kernel_launch(void* const* d_in, const int* in_sizes, int n_in,
                              void* d_out, int out_size, void* d_ws, size_t ws_size,
                              hipStream_t stream) {
    (void)in_sizes; (void)n_in; (void)out_size;
    const float* f1 = (const float*)d_in[0];
    const float* f2 = (const float*)d_in[1];
    float* ws = (float*)d_ws;

    // common carve
    float* fiN  = ws;                                  // 2*9216*64
    float* frN  = fiN + NITEM * HW * C;                // 2*9216*64
    float* ssn  = frN + NITEM * HW * C;                // 2*9216
    float* invn = ssn + NITEM * HW;                    // 2*8836
    float* after = invn + NITEM * NP;

    // factored-path carve (P buffer 64B-aligned)
    size_t afterOff = (size_t)(after - ws);
    afterOff = (afterOff + 63) & ~(size_t)63;
    float* pmat  = ws + afterOff;                      // 2*960*9216
    float* pbv   = pmat + (size_t)NITEM * PROWS * HW;  // 2*94*8836
    int*   pbi   = (int*)(pbv + (size_t)NITEM * HP * NP);
    float* flowhF = (float*)(pbi + (size_t)NITEM * HP * NP);
    float* flowwF = flowhF + NITEM * NP;
    size_t factored_words = (size_t)(flowwF + NITEM * NP - ws);
    bool use_factored = ws_size >= factored_words * sizeof(float);

    {
        int nthreads = 2 * NITEM * HW;
        normalize_kernel<<<(nthreads + 255) / 256, 256, 0, stream>>>(f1, f2, fiN, frN, ssn);
    }
    {
        int nthreads = NITEM * NP;
        refnorm_kernel<<<(nthreads + 255) / 256, 256, 0, stream>>>(ssn, invn);
    }

    if (use_factored) {
        for (int b = 0; b < NBAND; b++) {
            int ry0 = b * BRY;
            int bryb = (HP - ry0 < BRY) ? (HP - ry0) : BRY;
            dim3 ga(NPT, NQT, NITEM);
            gemmP_kernel<<<ga, 256, 0, stream>>>(fiN, frN, pmat, ry0);
            dim3 gb(bryb, NIT, NITEM);
            pass2_kernel<<<gb, 256, 0, stream>>>(pmat, invn, pbv, pbi, ry0);
        }
        {
            int nthreads = NITEM * NP;
            reduce94_kernel<<<(nthreads + 255) / 256, 256, 0, stream>>>(pbv, pbi, flowhF, flowwF);
            expand_kernel<<<(NITEM * 18 * HW + 255) / 256, 256, 0, stream>>>(flowhF, flowwF, (float*)d_out);
        }
    } else {
        // fallback carve (fits ~10 MB)
        float* bestv = after;                               // 2*8*8836
        int*   besti = (int*)(bestv + NITEM * NSEG * NP);
        float* flowh = (float*)(besti + NITEM * NSEG * NP);
        float* floww = flowh + NITEM * NP;
        dim3 grid(NMTILE, NSEG, NITEM);
        corr_kernel<<<grid, 256, 0, stream>>>(fiN, frN, invn, bestv, besti);
        int nthreads = NITEM * NP;
        reduce_flow_kernel<<<(nthreads + 255) / 256, 256, 0, stream>>>(bestv, besti, flowh, floww);
        expand_kernel<<<(NITEM * 18 * HW + 255) / 256, 256, 0, stream>>>(flowh, floww, (float*)d_out);
    }
}